// Round 16
// baseline (555.148 us; speedup 1.0000x reference)
//
#include <hip/hip_runtime.h>
#include <cstddef>

#define TPB 256

typedef __attribute__((ext_vector_type(8))) short short8v;   // 8 bf16
typedef __attribute__((ext_vector_type(4))) float f32x4;

__device__ __forceinline__ int rfl(int v) { return __builtin_amdgcn_readfirstlane(v); }
__device__ __forceinline__ float rflf(float v) {
    return __int_as_float(__builtin_amdgcn_readfirstlane(__float_as_int(v)));
}

// bf16 <-> f32 (RNE)
__device__ __forceinline__ unsigned short f2bf(float f) {
    union { float f; unsigned int u; } x{f};
    unsigned int r = x.u + 0x7fffu + ((x.u >> 16) & 1u);
    return (unsigned short)(r >> 16);
}
__device__ __forceinline__ float bf2f(unsigned short u) {
    return __uint_as_float(((unsigned int)u) << 16);
}

template <int N, int NW>
__device__ __forceinline__ void bredN(float* v, float* red) {
    __syncthreads();
    #pragma unroll
    for (int off = 32; off > 0; off >>= 1)
        #pragma unroll
        for (int i = 0; i < N; i++) v[i] += __shfl_down(v[i], off);
    const int lane = threadIdx.x & 63;
    const int wv = threadIdx.x >> 6;
    if (lane == 0)
        #pragma unroll
        for (int i = 0; i < N; i++) red[wv * N + i] = v[i];
    __syncthreads();
    if (threadIdx.x == 0) {
        #pragma unroll
        for (int i = 0; i < N; i++) {
            float s = 0.f;
            #pragma unroll
            for (int w = 0; w < NW; w++) s += red[w * N + i];
            red[i] = s;
        }
    }
    __syncthreads();
    #pragma unroll
    for (int i = 0; i < N; i++) v[i] = red[i];
}

__device__ __forceinline__ float silu_f(float v) {
    return v * __builtin_amdgcn_rcpf(1.f + __expf(-v));
}

struct GatePtrs { const float* wg[5]; };
struct WSrcs { const float* p[9]; };

// Pre-convert all expert GEMM weights to bf16 (once/launch).
__global__ __launch_bounds__(256) void wprep(WSrcs wsrc,
                                             unsigned short* __restrict__ whi) {
    const int sizes[9] = {4096, 8192, 16384, 32768, 65536, 131072, 131072, 65536, 32768};
    int idx = blockIdx.x * 256 + threadIdx.x;
    if (idx >= 487424) return;
    int rem = idx, s = 0;
    while (s < 8 && rem >= sizes[s]) { rem -= sizes[s]; s++; }
    whi[idx] = f2bf(wsrc.p[s][rem]);
}

__global__ void gate_kernel(const float* __restrict__ gi, GatePtrs gp,
                            const int* __restrict__ taskp,
                            int* __restrict__ gidx, float* __restrict__ gw) {
    const int s = blockIdx.x;
    const int b = threadIdx.x;
    const int task = taskp[0];
    const float* wg = gp.wg[s] + (size_t)task * 16 * 8;
    float l[8];
    #pragma unroll
    for (int e = 0; e < 8; e++) l[e] = 0.f;
    for (int d = 0; d < 16; d++) {
        float v = gi[b * 16 + d];
        #pragma unroll
        for (int e = 0; e < 8; e++) l[e] += v * wg[d * 8 + e];
    }
    float mx = l[0];
    #pragma unroll
    for (int e = 1; e < 8; e++) mx = fmaxf(mx, l[e]);
    float p[8]; float sum = 0.f;
    #pragma unroll
    for (int e = 0; e < 8; e++) { p[e] = expf(l[e] - mx); sum += p[e]; }
    int i0 = 0;
    #pragma unroll
    for (int e = 1; e < 8; e++) if (p[e] > p[i0]) i0 = e;
    int i1 = (i0 == 0) ? 1 : 0;
    #pragma unroll
    for (int e = 0; e < 8; e++) if (e != i0 && p[e] > p[i1]) i1 = e;
    const float denom = p[i0] + p[i1];
    const int base = (s * 64 + b) * 2;
    gidx[base] = i0; gidx[base + 1] = i1;
    gw[base] = p[i0] / denom; gw[base + 1] = p[i1] / denom;
}

// ============ MFMA GEMM: OUT[M][N] = W[M][K] x IN[K][N] per (b,slot) =======
// Grid: (b=64, nx, slot) — b innermost so XCD = b%8 (L2 locality per batch).
template <int M, int K, int N, int MT, int NCHK, bool FOLD, bool BIN>
__global__ __launch_bounds__(256) void gemm_bf16(
    const unsigned short* __restrict__ inp,
    const unsigned short* __restrict__ whi,
    const int* __restrict__ gidx, const float* __restrict__ foldStats,
    const float* __restrict__ foldS, const float* __restrict__ foldB,
    unsigned short* __restrict__ outp, float* __restrict__ stats,
    int mfull, int moff, int nchk1) {
    constexpr int KITERS = (K + 31) / 32;
    constexpr int IM = (MT == 64) ? 2 : 1;
    constexpr int IN = (MT == 16) ? 1 : 2;
    const int b = blockIdx.x;
    const int bx = blockIdx.y;
    const int nc = bx % NCHK, mc = bx / NCHK;
    const int slot = blockIdx.z;
    const int bs = b * 2 + slot;
    const int e = rfl(gidx[b * 2 + slot]);
    const int n0 = nc * 64, m0 = mc * MT;
    const int tid = threadIdx.x;
    const int lane = tid & 63, wv = tid >> 6;
    const int quad = lane >> 4, l15 = lane & 15;

    __shared__ __align__(16) unsigned short wtile[MT * 40];
    __shared__ unsigned int intile[16 * 65];
    __shared__ float sred[(MT / 4) * 2];
    __shared__ float afv[K], bfv[K];

    if (tid < (MT / 4) * 2) sred[tid] = 0.f;
    if constexpr (FOLD) {
        for (int c = tid; c < K; c += 256) {
            const int g = c >> 2;
            float s1 = 0.f, s2 = 0.f;
            for (int i = 0; i < nchk1; i++) {
                s1 += foldStats[(((size_t)bs * (K / 4) + g) * nchk1 + i) * 2 + 0];
                s2 += foldStats[(((size_t)bs * (K / 4) + g) * nchk1 + i) * 2 + 1];
            }
            const float mean = s1 / (4.f * N);
            const float var = s2 / (4.f * N) - mean * mean;
            const float inv = rsqrtf(var + 1e-5f);
            const float sc = foldS[e * K + c], bi = foldB[e * K + c];
            afv[c] = inv * sc;
            bfv[c] = bi - mean * inv * sc;
        }
    }

    int mbase, nbase;
    if constexpr (MT == 64) { mbase = (wv & 1) * 32; nbase = (wv >> 1) * 32; }
    else if constexpr (MT == 32) { mbase = (wv & 1) * 16; nbase = (wv >> 1) * 32; }
    else { mbase = 0; nbase = wv * 16; }

    f32x4 acc[IM][IN];
    #pragma unroll
    for (int im = 0; im < IM; im++)
        #pragma unroll
        for (int in = 0; in < IN; in++)
            #pragma unroll
            for (int r = 0; r < 4; r++) acc[im][in][r] = 0.f;

    const unsigned short* ib = inp + (size_t)(BIN ? b : bs) * K * N;
    const unsigned short* wbH = whi + ((size_t)e * mfull + moff) * K;

    for (int k0 = 0; k0 < KITERS * 32; k0 += 32) {
        __syncthreads();
        for (int i = tid; i < MT * 32; i += 256) {
            const int m = i >> 5, kk = i & 31;
            const bool ok = (k0 + kk < K);
            wtile[m * 40 + kk] = ok ? wbH[(size_t)(m0 + m) * K + k0 + kk]
                                    : (unsigned short)0;
        }
        {
            const int kp = tid >> 4, nq = tid & 15;
            const int k = k0 + kp * 2;
            const int n = n0 + nq * 4;
            unsigned short u0[4] = {0, 0, 0, 0}, u1[4] = {0, 0, 0, 0};
            const bool nv = (n < N);
            if (nv && k < K) {
                const ushort4 t = *(const ushort4*)(ib + (size_t)k * N + n);
                u0[0] = t.x; u0[1] = t.y; u0[2] = t.z; u0[3] = t.w;
            }
            if (nv && k + 1 < K) {
                const ushort4 t = *(const ushort4*)(ib + (size_t)(k + 1) * N + n);
                u1[0] = t.x; u1[1] = t.y; u1[2] = t.z; u1[3] = t.w;
            }
            #pragma unroll
            for (int t = 0; t < 4; t++) {
                float f0, f1;
                if constexpr (FOLD) {
                    f0 = (nv && k < K) ? silu_f(afv[k] * bf2f(u0[t]) + bfv[k]) : 0.f;
                    f1 = (nv && k + 1 < K) ? silu_f(afv[k + 1] * bf2f(u1[t]) + bfv[k + 1]) : 0.f;
                } else {
                    f0 = bf2f(u0[t]); f1 = bf2f(u1[t]);
                }
                intile[kp * 65 + nq * 4 + t] =
                    (unsigned int)f2bf(f0) | ((unsigned int)f2bf(f1) << 16);
            }
        }
        __syncthreads();

        short8v afr[IM];
        #pragma unroll
        for (int im = 0; im < IM; im++) {
            const int m = mbase + im * 16 + l15;
            afr[im] = *(const short8v*)&wtile[m * 40 + quad * 8];
        }
        #pragma unroll
        for (int in = 0; in < IN; in++) {
            union { unsigned int u[4]; short8v s; } bu;
            const int col = nbase + in * 16 + l15;
            #pragma unroll
            for (int i = 0; i < 4; i++) bu.u[i] = intile[(quad * 4 + i) * 65 + col];
            #pragma unroll
            for (int im = 0; im < IM; im++)
                acc[im][in] = __builtin_amdgcn_mfma_f32_16x16x32_bf16(
                    afr[im], bu.s, acc[im][in], 0, 0, 0);
        }
    }

    unsigned short* ob = outp + (size_t)bs * M * N;
    #pragma unroll
    for (int im = 0; im < IM; im++) {
        #pragma unroll
        for (int in = 0; in < IN; in++) {
            const int n = n0 + nbase + in * 16 + l15;
            float s1 = 0.f, s2 = 0.f;
            #pragma unroll
            for (int r = 0; r < 4; r++) {
                const float a = acc[im][in][r];
                s1 += a; s2 += a * a;
            }
            if (n < N) {
                #pragma unroll
                for (int r = 0; r < 4; r++) {
                    const int m = m0 + mbase + im * 16 + quad * 4 + r;
                    ob[(size_t)m * N + n] = f2bf(acc[im][in][r]);
                }
            }
            #pragma unroll
            for (int off = 8; off > 0; off >>= 1) {
                s1 += __shfl_down(s1, off, 16);
                s2 += __shfl_down(s2, off, 16);
            }
            if (l15 == 0) {
                const int gl = (mbase + im * 16) / 4 + quad;
                atomicAdd(&sred[gl * 2 + 0], s1);
                atomicAdd(&sred[gl * 2 + 1], s2);
            }
        }
    }
    __syncthreads();
    for (int i = tid; i < MT / 4; i += 256) {
        float* sp = stats + (((size_t)bs * (mfull / 4) + moff / 4 + mc * (MT / 4) + i)
                             * NCHK + nc) * 2;
        sp[0] = sred[i * 2]; sp[1] = sred[i * 2 + 1];
    }
}

// ============ dw kernel (3x3 stride 1; stages 2,4,5); grid (b, gch, slot) ===
template <int CLOC, int CFULL, int H, int W, int NCH, int TPBk, int NCHK1>
__global__ __launch_bounds__(TPBk) void dw_k(
    const unsigned short* __restrict__ raw1, const float* __restrict__ stats1,
    const float* __restrict__ g1s, const float* __restrict__ g1b,
    const float* __restrict__ w2, const int* __restrict__ gidx,
    unsigned short* __restrict__ act2raw, float* __restrict__ stats2, int coff) {
    constexpr int HW = H * W, HP = H + 2, WPL = W + 3;
    constexpr int NPV = HW / 4, NG = NCH / 4, NW = TPBk / 64;
    constexpr int Qc = HW / 4, QT = NCH * Qc, QI = (QT + TPBk - 1) / TPBk;
    constexpr int G1 = CFULL / 4;
    const int b = blockIdx.x, gch = blockIdx.y, slot = blockIdx.z;
    const int bs = b * 2 + slot;
    const int tid = threadIdx.x;
    const int e = rfl(gidx[b * 2 + slot]);
    const int cb0 = gch * NCH;
    const int cg0 = coff + cb0;

    __shared__ float buf1[NCH * HP * WPL];
    __shared__ float w2s[NCH * 9];
    __shared__ float afl[NCH], bfl[NCH];
    __shared__ float red[2 * NG * NW];

    for (int i = tid; i < NCH * HP * WPL; i += TPBk) buf1[i] = 0.f;
    if (tid < NCH * 9) w2s[tid] = w2[((size_t)e * CFULL + cg0) * 9 + tid];
    if (tid < NCH) {
        const int g = (cg0 + tid) >> 2;
        float s1 = 0.f, s2 = 0.f;
        for (int i = 0; i < NCHK1; i++) {
            s1 += stats1[(((size_t)bs * G1 + g) * NCHK1 + i) * 2 + 0];
            s2 += stats1[(((size_t)bs * G1 + g) * NCHK1 + i) * 2 + 1];
        }
        const float mean = s1 / (4.f * HW);
        const float var = s2 / (4.f * HW) - mean * mean;
        const float inv = rsqrtf(var + 1e-5f);
        const float sc = g1s[e * CFULL + cg0 + tid], bi = g1b[e * CFULL + cg0 + tid];
        afl[tid] = inv * sc; bfl[tid] = bi - mean * inv * sc;
    }
    __syncthreads();

    const unsigned short* rb = raw1 + (size_t)bs * CLOC * HW + (size_t)cb0 * HW;
    for (int i = tid; i < NCH * NPV; i += TPBk) {
        const int c = i / NPV, pv = i - c * NPV;
        const int p4 = pv * 4, ph = p4 / W, pwb = p4 - ph * W;
        const ushort4 u = *(const ushort4*)(rb + (size_t)c * HW + p4);
        const float a = afl[c], bb = bfl[c];
        float* bp = &buf1[(c * HP + ph + 1) * WPL + pwb + 1];
        bp[0] = silu_f(a * bf2f(u.x) + bb);
        bp[1] = silu_f(a * bf2f(u.y) + bb);
        bp[2] = silu_f(a * bf2f(u.z) + bb);
        bp[3] = silu_f(a * bf2f(u.w) + bb);
    }
    __syncthreads();

    float st2[2 * NG];
    #pragma unroll
    for (int i = 0; i < 2 * NG; i++) st2[i] = 0.f;
    unsigned short* ao = act2raw + (size_t)bs * CFULL * HW + (size_t)cg0 * HW;
    #pragma unroll
    for (int qi = 0; qi < QI; qi++) {
        const int q = tid + qi * TPBk;
        if (QI * TPBk == QT || q < QT) {
            const int c = q / Qc, qq = q - c * Qc;
            const int oh = qq % H, owb = (qq / H) * 4;
            float o[4] = {0.f, 0.f, 0.f, 0.f};
            #pragma unroll
            for (int kh = 0; kh < 3; kh++) {
                const int base = (c * HP + oh + kh) * WPL + owb;
                float r[6];
                #pragma unroll
                for (int i = 0; i < 6; i++) r[i] = buf1[base + i];
                const float wa = w2s[c * 9 + kh * 3 + 0];
                const float wb = w2s[c * 9 + kh * 3 + 1];
                const float wcc = w2s[c * 9 + kh * 3 + 2];
                #pragma unroll
                for (int t = 0; t < 4; t++)
                    o[t] += wa * r[t] + wb * r[t + 1] + wcc * r[t + 2];
            }
            ushort4 ov = {f2bf(o[0]), f2bf(o[1]), f2bf(o[2]), f2bf(o[3])};
            *(ushort4*)(ao + c * HW + oh * W + owb) = ov;
            #pragma unroll
            for (int t = 0; t < 4; t++) {
                if constexpr (NG == 1) { st2[0] += o[t]; st2[1] += o[t] * o[t]; }
                else {
                    const bool gs = (c >= 4);
                    float a0 = gs ? 0.f : o[t], a1 = gs ? o[t] : 0.f;
                    st2[0] += a0; st2[1] += a0 * a0;
                    st2[2] += a1; st2[3] += a1 * a1;
                }
            }
        }
    }
    bredN<2 * NG, NW>(st2, red);
    if (tid == 0) {
        #pragma unroll
        for (int g = 0; g < NG; g++) {
            stats2[((size_t)bs * G1 + cg0 / 4 + g) * 2 + 0] = st2[g * 2];
            stats2[((size_t)bs * G1 + cg0 / 4 + g) * 2 + 1] = st2[g * 2 + 1];
        }
    }
}

// ================= Stage 1: band pipeline ==================================
__global__ __launch_bounds__(256) void s1_stats(
    const float* __restrict__ xin, const float* __restrict__ w1,
    const int* __restrict__ gidx, float* __restrict__ stats1) {
    const int b = blockIdx.x, g = blockIdx.y, slot = blockIdx.z;
    const int tid = threadIdx.x;
    const int e = rfl(gidx[b * 2 + slot]);
    __shared__ float red[8];
    const float* xb = xin + (size_t)b * 3 * 6400;
    const float* w1e = w1 + ((size_t)e * 32 + g * 4) * 3;
    float wr[4][3];
    #pragma unroll
    for (int c = 0; c < 4; c++)
        #pragma unroll
        for (int k = 0; k < 3; k++) wr[c][k] = rflf(w1e[c * 3 + k]);
    float s[2] = {0.f, 0.f};
    #pragma unroll
    for (int j = 0; j < 7; j++) {
        const int i = j * 256 + tid;
        if (i < 1600) {
            const int p4 = i * 4;
            const float4 v0 = *(const float4*)(xb + p4);
            const float4 v1 = *(const float4*)(xb + 6400 + p4);
            const float4 v2 = *(const float4*)(xb + 12800 + p4);
            const float a0[4] = {v0.x, v0.y, v0.z, v0.w};
            const float a1[4] = {v1.x, v1.y, v1.z, v1.w};
            const float a2[4] = {v2.x, v2.y, v2.z, v2.w};
            #pragma unroll
            for (int t = 0; t < 4; t++)
                #pragma unroll
                for (int c = 0; c < 4; c++) {
                    float a = fmaf(wr[c][0], a0[t], fmaf(wr[c][1], a1[t], wr[c][2] * a2[t]));
                    s[0] += a; s[1] += a * a;
                }
        }
    }
    bredN<2, 4>(s, red);
    if (tid == 0) {
        float* sp = stats1 + ((size_t)(b * 2 + slot) * 8 + g) * 2;
        sp[0] = s[0]; sp[1] = s[1];
    }
}

// Row-interleaved even/odd band kernel (grid b, gb, slot); rawdw bf16 out.
__global__ __launch_bounds__(256) void s1_band(
    const float* __restrict__ xin, const float* __restrict__ w1,
    const float* __restrict__ g1s, const float* __restrict__ g1b,
    const float* __restrict__ w2, const int* __restrict__ gidx,
    const float* __restrict__ stats1,
    unsigned short* __restrict__ rawdw, float* __restrict__ stats2) {
    constexpr int NR = 25, RW = 91, EVO = 44;
    const int b = blockIdx.x;
    const int gb = blockIdx.y;
    const int g = gb >> 2, band = gb & 3;
    const int slot = blockIdx.z;
    const int tid = threadIdx.x;
    const int e = rfl(gidx[b * 2 + slot]);

    __shared__ float sbuf[4 * NR * RW];
    __shared__ float w2s[196];
    __shared__ float red[8];

    for (int i = tid; i < 4 * NR * RW; i += 256) sbuf[i] = 0.f;
    if (tid < 196) w2s[tid] = w2[((size_t)e * 32 + g * 4) * 49 + tid];

    const float* sp = stats1 + ((size_t)(b * 2 + slot) * 8 + g) * 2;
    const float s1v = rflf(sp[0]), s2v = rflf(sp[1]);
    const float mean = s1v / 25600.f;
    const float var = s2v / 25600.f - mean * mean;
    const float inv = rsqrtf(var + 1e-5f);

    const float* xb = xin + (size_t)b * 3 * 6400;
    const float* w1e = w1 + ((size_t)e * 32 + g * 4) * 3;
    float wr[4][3], sc1r[4], bi1r[4];
    #pragma unroll
    for (int c = 0; c < 4; c++) {
        #pragma unroll
        for (int k = 0; k < 3; k++) wr[c][k] = rflf(w1e[c * 3 + k]);
        sc1r[c] = rflf(g1s[e * 32 + g * 4 + c]);
        bi1r[c] = rflf(g1b[e * 32 + g * 4 + c]);
    }
    const int oh0 = band * 10;
    const int rlo = 2 * oh0 - 3;
    __syncthreads();

    for (int ii = tid; ii < 500; ii += 256) {
        const int p4 = ii * 4;
        const int l = p4 / 80, pw = p4 - l * 80;
        const int r = rlo + l;
        if (r >= 0 && r < 80) {
            const int lrow = (l >> 1) + (l & 1) * 13;
            const float4 v0 = *(const float4*)(xb + r * 80 + pw);
            const float4 v1 = *(const float4*)(xb + 6400 + r * 80 + pw);
            const float4 v2 = *(const float4*)(xb + 12800 + r * 80 + pw);
            const float a0[4] = {v0.x, v0.y, v0.z, v0.w};
            const float a1[4] = {v1.x, v1.y, v1.z, v1.w};
            const float a2[4] = {v2.x, v2.y, v2.z, v2.w};
            #pragma unroll
            for (int c = 0; c < 4; c++) {
                #pragma unroll
                for (int t = 0; t < 4; t++) {
                    float a = fmaf(wr[c][0], a0[t], fmaf(wr[c][1], a1[t], wr[c][2] * a2[t]));
                    float v = silu_f((a - mean) * inv * sc1r[c] + bi1r[c]);
                    const int cc = pw + t + 3;
                    const int sl = (cc & 1) ? EVO + (cc >> 1) : (cc >> 1);
                    sbuf[(c * NR + lrow) * RW + sl] = v;
                }
            }
        }
    }
    __syncthreads();

    float st2[2] = {0.f, 0.f};
    unsigned short* rw = rawdw + (size_t)(b * 2 + slot) * 32 * 1600
                         + (size_t)g * 4 * 1600;
    #pragma unroll
    for (int qi = 0; qi < 2; qi++) {
        const int q = tid + qi * 256;
        if (q < 400) {
            const int c = q / 100;
            const int rem = q - c * 100;
            const int ohl = rem % 10, owb = (rem / 10) * 4;
            float o[4] = {0.f, 0.f, 0.f, 0.f};
            #pragma unroll
            for (int kh = 0; kh < 7; kh++) {
                const int lrow = ohl + (kh >> 1) + (kh & 1) * 13;
                const int base = (c * NR + lrow) * RW;
                const float2 e01 = *(const float2*)&sbuf[base + owb];
                const float2 e23 = *(const float2*)&sbuf[base + owb + 2];
                const float2 e45 = *(const float2*)&sbuf[base + owb + 4];
                const float e6 = sbuf[base + owb + 6];
                const float2 q01 = *(const float2*)&sbuf[base + EVO + owb];
                const float2 q23 = *(const float2*)&sbuf[base + EVO + owb + 2];
                const float2 q45 = *(const float2*)&sbuf[base + EVO + owb + 4];
                const float evr[7] = {e01.x, e01.y, e23.x, e23.y, e45.x, e45.y, e6};
                const float odr[6] = {q01.x, q01.y, q23.x, q23.y, q45.x, q45.y};
                const float w0 = w2s[c * 49 + kh * 7 + 0];
                const float w1v = w2s[c * 49 + kh * 7 + 1];
                const float w2v = w2s[c * 49 + kh * 7 + 2];
                const float w3 = w2s[c * 49 + kh * 7 + 3];
                const float w4 = w2s[c * 49 + kh * 7 + 4];
                const float w5 = w2s[c * 49 + kh * 7 + 5];
                const float w6 = w2s[c * 49 + kh * 7 + 6];
                #pragma unroll
                for (int t = 0; t < 4; t++)
                    o[t] += w0 * evr[t] + w1v * odr[t] + w2v * evr[t + 1]
                          + w3 * odr[t + 1] + w4 * evr[t + 2] + w5 * odr[t + 2]
                          + w6 * evr[t + 3];
            }
            const int oh = oh0 + ohl;
            ushort4 ov = {f2bf(o[0]), f2bf(o[1]), f2bf(o[2]), f2bf(o[3])};
            *(ushort4*)(rw + c * 1600 + oh * 40 + owb) = ov;
            #pragma unroll
            for (int t = 0; t < 4; t++) { st2[0] += o[t]; st2[1] += o[t] * o[t]; }
        }
    }
    bredN<2, 4>(st2, red);
    if (tid == 0) {
        float* s2p = stats2 + (((size_t)(b * 2 + slot) * 8 + g) * 4 + band) * 2;
        s2p[0] = st2[0]; s2p[1] = st2[1];
    }
}

// ======== Stage-3 SLOT-MERGED fused ab (CIN=32, CEXP=128, stride-2 3x3) ====
// One block computes both slots' 4-ch group: x tile loaded ONCE. Grid (b, gch).
__global__ __launch_bounds__(256) void dsc_ab_s3(
    const unsigned short* __restrict__ xin, const float* __restrict__ w1,
    const float* __restrict__ g1s, const float* __restrict__ g1b,
    const float* __restrict__ w2,
    const float* __restrict__ g2s, const float* __restrict__ g2b,
    const int* __restrict__ gidx, unsigned short* __restrict__ act2) {
    constexpr int CIN = 32, CEXP = 128, H = 40, W = 40, HW = 1600;
    constexpr int HO = 20, WO = 20, HWO = 400;
    constexpr int HP = H + 2, WPL = W + 3, EVW = (W + 2) / 2;
    const int b = blockIdx.x, gch = blockIdx.y;
    const int cb0 = gch * 4;
    const int tid = threadIdx.x;
    int ee[2];
    ee[0] = rfl(gidx[b * 2 + 0]);
    ee[1] = rfl(gidx[b * 2 + 1]);

    __shared__ float buf1[4 * HP * WPL];   // 28.9 KB
    __shared__ float w2s[2][36];
    __shared__ float sc2s[2][4], bi2s[2][4];
    __shared__ float red[16];

    for (int i = tid; i < 4 * HP * WPL; i += 256) buf1[i] = 0.f;
    if (tid < 72) {
        const int s = tid / 36, i = tid - s * 36;
        w2s[s][i] = w2[((size_t)ee[s] * CEXP + cb0) * 9 + i];
    }
    if (tid < 8) {
        const int s = tid >> 2, c = tid & 3;
        sc2s[s][c] = g2s[ee[s] * CEXP + cb0 + c];
        bi2s[s][c] = g2b[ee[s] * CEXP + cb0 + c];
    }

    const unsigned short* xb = xin + (size_t)b * CIN * HW;

    // pw1 for BOTH slots: acc[s][c][j][t]
    float acc[2][4][2][4];
    #pragma unroll
    for (int s = 0; s < 2; s++)
        #pragma unroll
        for (int c = 0; c < 4; c++)
            #pragma unroll
            for (int j = 0; j < 2; j++)
                #pragma unroll
                for (int t = 0; t < 4; t++) acc[s][c][j][t] = 0.f;

    for (int cb = 0; cb < CIN; cb += 4) {
        float wr[2][4][4];
        #pragma unroll
        for (int s = 0; s < 2; s++) {
            const float* w1e = w1 + ((size_t)ee[s] * CEXP + cb0) * CIN;
            #pragma unroll
            for (int c = 0; c < 4; c++)
                #pragma unroll
                for (int k = 0; k < 4; k++)
                    wr[s][c][k] = rflf(w1e[c * CIN + cb + k]);
        }
        #pragma unroll
        for (int j = 0; j < 2; j++) {
            const int pv = tid + j * 256;
            if (pv < 400) {
                #pragma unroll
                for (int k = 0; k < 4; k++) {
                    const ushort4 v4 = *(const ushort4*)(xb + (cb + k) * HW + pv * 4);
                    const float va[4] = {bf2f(v4.x), bf2f(v4.y), bf2f(v4.z), bf2f(v4.w)};
                    #pragma unroll
                    for (int s = 0; s < 2; s++)
                        #pragma unroll
                        for (int c = 0; c < 4; c++)
                            #pragma unroll
                            for (int t = 0; t < 4; t++)
                                acc[s][c][j][t] = fmaf(wr[s][c][k], va[t], acc[s][c][j][t]);
                }
            }
        }
    }
    // GN1 stats for both slots (each slot's 4ch = one group).
    float st[4] = {0.f, 0.f, 0.f, 0.f};
    #pragma unroll
    for (int s = 0; s < 2; s++)
        #pragma unroll
        for (int c = 0; c < 4; c++)
            #pragma unroll
            for (int j = 0; j < 2; j++)
                #pragma unroll
                for (int t = 0; t < 4; t++) {
                    const float a = acc[s][c][j][t];
                    st[s * 2] += a; st[s * 2 + 1] += a * a;
                }
    bredN<4, 4>(st, red);
    float mg[2], ig[2], sc1r[2][4], bi1r[2][4];
    #pragma unroll
    for (int s = 0; s < 2; s++) {
        mg[s] = st[s * 2] / 6400.f;
        const float var = st[s * 2 + 1] / 6400.f - mg[s] * mg[s];
        ig[s] = rsqrtf(var + 1e-5f);
        #pragma unroll
        for (int c = 0; c < 4; c++) {
            sc1r[s][c] = rflf(g1s[ee[s] * CEXP + cb0 + c]);
            bi1r[s][c] = rflf(g1b[ee[s] * CEXP + cb0 + c]);
        }
    }

    // Per-slot: buf1 <- silu(GN1(acc[s])), dw -> dacc[s], GN2 stats.
    float dacc[2][2][4];
    float st2[4] = {0.f, 0.f, 0.f, 0.f};
    #pragma unroll
    for (int s = 0; s < 2; s++) {
        if (s) __syncthreads();   // slot-0 dw reads complete before overwrite
        #pragma unroll
        for (int j = 0; j < 2; j++) {
            const int pv = tid + j * 256;
            if (pv < 400) {
                const int p4 = pv * 4;
                const int ph = p4 / W, pwb = p4 - ph * W;
                #pragma unroll
                for (int c = 0; c < 4; c++) {
                    #pragma unroll
                    for (int t = 0; t < 4; t++) {
                        const float v = silu_f((acc[s][c][j][t] - mg[s]) * ig[s]
                                               * sc1r[s][c] + bi1r[s][c]);
                        const int j2 = pwb + t + 1;
                        const int col = (j2 & 1) ? EVW + (j2 >> 1) : (j2 >> 1);
                        buf1[(c * HP + ph + 1) * WPL + col] = v;
                    }
                }
            }
        }
        __syncthreads();
        #pragma unroll
        for (int qi = 0; qi < 2; qi++) {
            #pragma unroll
            for (int t = 0; t < 4; t++) dacc[s][qi][t] = 0.f;
            const int q = tid + qi * 256;
            if (q < 400) {
                const int c = q / 100, qq = q - c * 100;
                const int oh = qq % HO, owb = (qq / HO) * 4;
                float o[4] = {0.f, 0.f, 0.f, 0.f};
                #pragma unroll
                for (int kh = 0; kh < 3; kh++) {
                    const int base = (c * HP + 2 * oh + kh) * WPL;
                    float ev[5], od[4];
                    #pragma unroll
                    for (int i = 0; i < 5; i++) ev[i] = buf1[base + owb + i];
                    #pragma unroll
                    for (int i = 0; i < 4; i++) od[i] = buf1[base + EVW + owb + i];
                    const float wa = w2s[s][c * 9 + kh * 3 + 0];
                    const float wb = w2s[s][c * 9 + kh * 3 + 1];
                    const float wcc = w2s[s][c * 9 + kh * 3 + 2];
                    #pragma unroll
                    for (int t = 0; t < 4; t++)
                        o[t] += wa * ev[t] + wb * od[t] + wcc * ev[t + 1];
                }
                #pragma unroll
                for (int t = 0; t < 4; t++) {
                    dacc[s][qi][t] = o[t];
                    st2[s * 2] += o[t]; st2[s * 2 + 1] += o[t] * o[t];
                }
            }
        }
    }
    bredN<4, 4>(st2, red);
    #pragma unroll
    for (int s = 0; s < 2; s++) {
        const float m2 = st2[s * 2] / 1600.f;
        const float var2 = st2[s * 2 + 1] / 1600.f - m2 * m2;
        const float i2 = rsqrtf(var2 + 1e-5f);
        unsigned short* ao = act2 + ((size_t)(b * 2 + s) * CEXP + cb0) * HWO;
        #pragma unroll
        for (int qi = 0; qi < 2; qi++) {
            const int q = tid + qi * 256;
            if (q < 400) {
                const int c = q / 100, qq = q - c * 100;
                const int oh = qq % HO, owb = (qq / HO) * 4;
                const float sc = sc2s[s][c], bi = bi2s[s][c];
                ushort4 ov;
                ov.x = f2bf(silu_f((dacc[s][qi][0] - m2) * i2 * sc + bi));
                ov.y = f2bf(silu_f((dacc[s][qi][1] - m2) * i2 * sc + bi));
                ov.z = f2bf(silu_f((dacc[s][qi][2] - m2) * i2 * sc + bi));
                ov.w = f2bf(silu_f((dacc[s][qi][3] - m2) * i2 * sc + bi));
                *(ushort4*)(ao + c * HWO + oh * WO + owb) = ov;
            }
        }
    }
}

// k3m: fold GN3 stat partials -> (A,B), combine slots. Grid (b, gg).
template <int COUT, int HWO, int PXC, bool PATCH>
__global__ __launch_bounds__(256) void pw3_k3m(
    const unsigned short* __restrict__ raw3, const float* __restrict__ statsw,
    const float* __restrict__ g3s, const float* __restrict__ g3b,
    const int* __restrict__ gidx, const float* __restrict__ gw,
    const float* __restrict__ ppe, float* __restrict__ outf,
    unsigned short* __restrict__ outb) {
    constexpr int G = COUT / 4;
    constexpr int Q = HWO / 4;
    const int b = blockIdx.x, gg = blockIdx.y;
    const int tid = threadIdx.x;

    float A[2][4], Bv[2][4];
    #pragma unroll
    for (int slot = 0; slot < 2; slot++) {
        const int e = rfl(gidx[b * 2 + slot]);
        const float wgt = rflf(gw[b * 2 + slot]);
        const float* sp = statsw + ((size_t)(b * 2 + slot) * G + gg) * PXC * 2;
        float s1 = 0.f, s2 = 0.f;
        for (int i = 0; i < PXC; i++) { s1 += rflf(sp[i * 2]); s2 += rflf(sp[i * 2 + 1]); }
        const float mean = s1 / (4.f * HWO);
        const float var = s2 / (4.f * HWO) - mean * mean;
        const float inv = rsqrtf(var + 1e-5f);
        #pragma unroll
        for (int i = 0; i < 4; i++) {
            const int c = gg * 4 + i;
            const float sc = rflf(g3s[e * COUT + c]);
            const float bi = rflf(g3b[e * COUT + c]);
            A[slot][i] = wgt * inv * sc;
            Bv[slot][i] = wgt * (bi - mean * inv * sc);
        }
    }

    #pragma unroll
    for (int i = 0; i < 4; i++) {
        const int c = gg * 4 + i;
        const unsigned short* r0 = raw3 + ((size_t)(b * 2 + 0) * COUT + c) * HWO;
        const unsigned short* r1 = raw3 + ((size_t)(b * 2 + 1) * COUT + c) * HWO;
        for (int q = tid; q < Q; q += 256) {
            const int p4 = q * 4;
            const ushort4 u0 = *(const ushort4*)(r0 + p4);
            const ushort4 u1 = *(const ushort4*)(r1 + p4);
            const float v0[4] = {bf2f(u0.x), bf2f(u0.y), bf2f(u0.z), bf2f(u0.w)};
            const float v1[4] = {bf2f(u1.x), bf2f(u1.y), bf2f(u1.z), bf2f(u1.w)};
            float o[4];
            #pragma unroll
            for (int t = 0; t < 4; t++)
                o[t] = fmaf(A[0][i], v0[t], Bv[0][i]) + fmaf(A[1][i], v1[t], Bv[1][i]);
            if constexpr (!PATCH) {
                ushort4 ov = {f2bf(o[0]), f2bf(o[1]), f2bf(o[2]), f2bf(o[3])};
                *(ushort4*)(outb + ((size_t)b * COUT + c) * HWO + p4) = ov;
            } else {
                const int ph = p4 / 20, pw0 = p4 - ph * 20;
                const int p = (ph >> 2) * 5 + (pw0 >> 2);
                const int dbase = ((ph & 3) * 4) * 32 + c;
                float* op = outf + ((size_t)b * 25 + p) * 512;
                const float* pp = ppe + p * 512;
                #pragma unroll
                for (int jj = 0; jj < 4; jj++)
                    op[dbase + jj * 32] = o[jj] + pp[dbase + jj * 32];
            }
        }
    }
    if (PATCH && gg == 0 && b == 0 && tid == 0) outf[64 * 25 * 512] = 0.f;
}

extern "C" void kernel_launch(void* const* d_in, const int* in_sizes, int n_in,
                              void* d_out, int out_size, void* d_ws, size_t ws_size,
                              hipStream_t stream) {
    const float* gate_input = (const float*)d_in[0];
    const float* expert_input = (const float*)d_in[1];
    const float* ppe = (const float*)d_in[2];
    const int* taskp = (const int*)d_in[53];
    auto in = [&](int s, int k) { return (const float*)d_in[3 + s * 10 + k]; };
    // k: 0 wg, 1 w1, 2 g1s, 3 g1b, 4 w2, 5 g2s, 6 g2b, 7 w3, 8 g3s, 9 g3b

    char* ws = (char*)d_ws;
    int* gidx = (int*)ws;
    float* gw = (float*)(ws + 4096);
    size_t off = 8192;
    unsigned short* x0 = (unsigned short*)(ws + off); off += (size_t)8 << 20;
    unsigned short* x1 = (unsigned short*)(ws + off); off += (size_t)8 << 20;
    unsigned short* act2 = (unsigned short*)(ws + off); off += (size_t)27 << 20;
    char* bufA = ws + off; off += (size_t)27 << 20;   // raw1 / raw3 / s1 rawdw
    float* stats1 = (float*)(ws + off); off += (size_t)2 << 20;
    float* stats2 = (float*)(ws + off); off += 262144;
    float* stats3 = (float*)(ws + off); off += (size_t)1 << 20;
    float* st1a = (float*)(ws + off); off += 65536;
    float* st1b = (float*)(ws + off); off += 65536;
    unsigned short* whi = (unsigned short*)(ws + off); off += 487424 * 2;
    float* outp = (float*)d_out;
    unsigned short* bufA16 = (unsigned short*)bufA;

    WSrcs wsrc;
    wsrc.p[0] = in(0, 7); wsrc.p[1] = in(1, 1); wsrc.p[2] = in(1, 7);
    wsrc.p[3] = in(2, 1); wsrc.p[4] = in(2, 7); wsrc.p[5] = in(3, 1);
    wsrc.p[6] = in(3, 7); wsrc.p[7] = in(4, 1); wsrc.p[8] = in(4, 7);

    GatePtrs gp;
    for (int s = 0; s < 5; s++) gp.wg[s] = in(s, 0);
    gate_kernel<<<5, 64, 0, stream>>>(gate_input, gp, taskp, gidx, gw);
    wprep<<<(487424 + 255) / 256, 256, 0, stream>>>(wsrc, whi);

    // ---- Stage 1: stats -> band(rawdw bf16) -> GEMM(fold GN2) -> k3m ----
    s1_stats<<<dim3(64, 8, 2), 256, 0, stream>>>(expert_input, in(0, 1),
                                                 gidx + 0 * 128, st1a);
    s1_band<<<dim3(64, 32, 2), 256, 0, stream>>>(
        expert_input, in(0, 1), in(0, 2), in(0, 3), in(0, 4),
        gidx + 0 * 128, st1a, bufA16, st1b);
    gemm_bf16<16, 32, 1600, 16, 25, true, false><<<dim3(64, 25, 2), 256, 0, stream>>>(
        bufA16, whi + 0, gidx + 0 * 128, st1b, in(0, 5), in(0, 6),
        act2, stats3, 16, 0, 4);
    pw3_k3m<16, 1600, 25, false><<<dim3(64, 4), 256, 0, stream>>>(
        act2, stats3, in(0, 8), in(0, 9), gidx + 0 * 128,
        gw + 0 * 128, ppe, nullptr, x0);

    // ---- Stage 2 ----
    gemm_bf16<64, 16, 1600, 64, 25, false, true><<<dim3(64, 25, 2), 256, 0, stream>>>(
        x0, whi + 4096, gidx + 1 * 128, nullptr, nullptr, nullptr,
        bufA16, stats1, 64, 0, 1);
    dw_k<64, 64, 40, 40, 4, 256, 25><<<dim3(64, 16, 2), 256, 0, stream>>>(
        bufA16, stats1, in(1, 2), in(1, 3), in(1, 4),
        gidx + 1 * 128, act2, stats2, 0);
    gemm_bf16<32, 64, 1600, 32, 25, true, false><<<dim3(64, 25, 2), 256, 0, stream>>>(
        act2, whi + 12288, gidx + 1 * 128, stats2, in(1, 5), in(1, 6),
        bufA16, stats3, 32, 0, 1);
    pw3_k3m<32, 1600, 25, false><<<dim3(64, 8), 256, 0, stream>>>(
        bufA16, stats3, in(1, 8), in(1, 9), gidx + 1 * 128,
        gw + 1 * 128, ppe, nullptr, x1);

    // ---- Stage 3: slot-merged fused ab + MFMA pw3 ----
    dsc_ab_s3<<<dim3(64, 32), 256, 0, stream>>>(
        x1, in(2, 1), in(2, 2), in(2, 3), in(2, 4), in(2, 5), in(2, 6),
        gidx + 2 * 128, act2);
    gemm_bf16<64, 128, 400, 64, 7, false, false><<<dim3(64, 7, 2), 256, 0, stream>>>(
        act2, whi + 61440, gidx + 2 * 128, nullptr, nullptr, nullptr,
        bufA16, stats3, 64, 0, 1);
    pw3_k3m<64, 400, 7, false><<<dim3(64, 16), 256, 0, stream>>>(
        bufA16, stats3, in(2, 8), in(2, 9), gidx + 2 * 128,
        gw + 2 * 128, ppe, nullptr, x0);

    // ---- Stage 4 ----
    gemm_bf16<256, 64, 400, 64, 7, false, true><<<dim3(64, 28, 2), 256, 0, stream>>>(
        x0, whi + 126976, gidx + 3 * 128, nullptr, nullptr, nullptr,
        bufA16, stats1, 256, 0, 1);
    dw_k<256, 256, 20, 20, 8, 128, 7><<<dim3(64, 32, 2), 128, 0, stream>>>(
        bufA16, stats1, in(3, 2), in(3, 3), in(3, 4),
        gidx + 3 * 128, act2, stats2, 0);
    gemm_bf16<64, 256, 400, 64, 7, true, false><<<dim3(64, 7, 2), 256, 0, stream>>>(
        act2, whi + 258048, gidx + 3 * 128, stats2, in(3, 5), in(3, 6),
        bufA16, stats3, 64, 0, 1);
    pw3_k3m<64, 400, 7, false><<<dim3(64, 16), 256, 0, stream>>>(
        bufA16, stats3, in(3, 8), in(3, 9), gidx + 3 * 128,
        gw + 3 * 128, ppe, nullptr, x1);

    // ---- Stage 5 (+ fused patchify) ----
    gemm_bf16<128, 64, 400, 64, 7, false, true><<<dim3(64, 14, 2), 256, 0, stream>>>(
        x1, whi + 389120, gidx + 4 * 128, nullptr, nullptr, nullptr,
        bufA16, stats1, 128, 0, 1);
    dw_k<128, 128, 20, 20, 8, 128, 7><<<dim3(64, 16, 2), 128, 0, stream>>>(
        bufA16, stats1, in(4, 2), in(4, 3), in(4, 4),
        gidx + 4 * 128, act2, stats2, 0);
    gemm_bf16<32, 128, 400, 32, 7, true, false><<<dim3(64, 7, 2), 256, 0, stream>>>(
        act2, whi + 454656, gidx + 4 * 128, stats2, in(4, 5), in(4, 6),
        bufA16, stats3, 32, 0, 1);
    pw3_k3m<32, 400, 7, true><<<dim3(64, 8), 256, 0, stream>>>(
        bufA16, stats3, in(4, 8), in(4, 9), gidx + 4 * 128,
        gw + 4 * 128, ppe, outp, nullptr);
}

// Round 17
// 491.417 us; speedup vs baseline: 1.1297x; 1.1297x over previous
//
#include <hip/hip_runtime.h>
#include <cstddef>

#define TPB 256

typedef __attribute__((ext_vector_type(8))) short short8v;   // 8 bf16
typedef __attribute__((ext_vector_type(4))) float f32x4;

__device__ __forceinline__ int rfl(int v) { return __builtin_amdgcn_readfirstlane(v); }
__device__ __forceinline__ float rflf(float v) {
    return __int_as_float(__builtin_amdgcn_readfirstlane(__float_as_int(v)));
}

// bf16 <-> f32 (RNE)
__device__ __forceinline__ unsigned short f2bf(float f) {
    union { float f; unsigned int u; } x{f};
    unsigned int r = x.u + 0x7fffu + ((x.u >> 16) & 1u);
    return (unsigned short)(r >> 16);
}
__device__ __forceinline__ float bf2f(unsigned short u) {
    return __uint_as_float(((unsigned int)u) << 16);
}

template <int N, int NW>
__device__ __forceinline__ void bredN(float* v, float* red) {
    __syncthreads();
    #pragma unroll
    for (int off = 32; off > 0; off >>= 1)
        #pragma unroll
        for (int i = 0; i < N; i++) v[i] += __shfl_down(v[i], off);
    const int lane = threadIdx.x & 63;
    const int wv = threadIdx.x >> 6;
    if (lane == 0)
        #pragma unroll
        for (int i = 0; i < N; i++) red[wv * N + i] = v[i];
    __syncthreads();
    if (threadIdx.x == 0) {
        #pragma unroll
        for (int i = 0; i < N; i++) {
            float s = 0.f;
            #pragma unroll
            for (int w = 0; w < NW; w++) s += red[w * N + i];
            red[i] = s;
        }
    }
    __syncthreads();
    #pragma unroll
    for (int i = 0; i < N; i++) v[i] = red[i];
}

__device__ __forceinline__ float silu_f(float v) {
    return v * __builtin_amdgcn_rcpf(1.f + __expf(-v));
}

struct GatePtrs { const float* wg[5]; };
struct WSrcs { const float* p[9]; };

// Pre-convert all expert GEMM weights to bf16 (once/launch).
__global__ __launch_bounds__(256) void wprep(WSrcs wsrc,
                                             unsigned short* __restrict__ whi) {
    const int sizes[9] = {4096, 8192, 16384, 32768, 65536, 131072, 131072, 65536, 32768};
    int idx = blockIdx.x * 256 + threadIdx.x;
    if (idx >= 487424) return;
    int rem = idx, s = 0;
    while (s < 8 && rem >= sizes[s]) { rem -= sizes[s]; s++; }
    whi[idx] = f2bf(wsrc.p[s][rem]);
}

__global__ void gate_kernel(const float* __restrict__ gi, GatePtrs gp,
                            const int* __restrict__ taskp,
                            int* __restrict__ gidx, float* __restrict__ gw) {
    const int s = blockIdx.x;
    const int b = threadIdx.x;
    const int task = taskp[0];
    const float* wg = gp.wg[s] + (size_t)task * 16 * 8;
    float l[8];
    #pragma unroll
    for (int e = 0; e < 8; e++) l[e] = 0.f;
    for (int d = 0; d < 16; d++) {
        float v = gi[b * 16 + d];
        #pragma unroll
        for (int e = 0; e < 8; e++) l[e] += v * wg[d * 8 + e];
    }
    float mx = l[0];
    #pragma unroll
    for (int e = 1; e < 8; e++) mx = fmaxf(mx, l[e]);
    float p[8]; float sum = 0.f;
    #pragma unroll
    for (int e = 0; e < 8; e++) { p[e] = expf(l[e] - mx); sum += p[e]; }
    int i0 = 0;
    #pragma unroll
    for (int e = 1; e < 8; e++) if (p[e] > p[i0]) i0 = e;
    int i1 = (i0 == 0) ? 1 : 0;
    #pragma unroll
    for (int e = 0; e < 8; e++) if (e != i0 && p[e] > p[i1]) i1 = e;
    const float denom = p[i0] + p[i1];
    const int base = (s * 64 + b) * 2;
    gidx[base] = i0; gidx[base + 1] = i1;
    gw[base] = p[i0] / denom; gw[base + 1] = p[i1] / denom;
}

// ============ MFMA GEMM: OUT[M][N] = W[M][K] x IN[K][N] per (b,slot) =======
// BIN=true: input per-BATCH [64][K][N] (pw1). BIN=false: per-(b,slot) (pw3).
// FOLD: GN affine+silu folded on input load; stats summed over nchk1 partials.
template <int M, int K, int N, int MT, int NCHK, bool FOLD, bool BIN>
__global__ __launch_bounds__(256) void gemm_bf16(
    const unsigned short* __restrict__ inp,
    const unsigned short* __restrict__ whi,
    const int* __restrict__ gidx, const float* __restrict__ foldStats,
    const float* __restrict__ foldS, const float* __restrict__ foldB,
    unsigned short* __restrict__ outp, float* __restrict__ stats,
    int mfull, int moff, int nchk1) {
    constexpr int KITERS = (K + 31) / 32;
    constexpr int IM = (MT == 64) ? 2 : 1;
    constexpr int IN = (MT == 16) ? 1 : 2;
    const int bx = blockIdx.x;
    const int nc = bx % NCHK, mc = bx / NCHK;
    const int b = blockIdx.y, slot = blockIdx.z;
    const int bs = b * 2 + slot;
    const int e = rfl(gidx[b * 2 + slot]);
    const int n0 = nc * 64, m0 = mc * MT;
    const int tid = threadIdx.x;
    const int lane = tid & 63, wv = tid >> 6;
    const int quad = lane >> 4, l15 = lane & 15;

    __shared__ __align__(16) unsigned short wtile[MT * 40];
    __shared__ unsigned int intile[16 * 65];
    __shared__ float sred[(MT / 4) * 2];
    __shared__ float afv[K], bfv[K];

    if (tid < (MT / 4) * 2) sred[tid] = 0.f;
    if constexpr (FOLD) {
        for (int c = tid; c < K; c += 256) {
            const int g = c >> 2;
            float s1 = 0.f, s2 = 0.f;
            for (int i = 0; i < nchk1; i++) {
                s1 += foldStats[(((size_t)bs * (K / 4) + g) * nchk1 + i) * 2 + 0];
                s2 += foldStats[(((size_t)bs * (K / 4) + g) * nchk1 + i) * 2 + 1];
            }
            const float mean = s1 / (4.f * N);
            const float var = s2 / (4.f * N) - mean * mean;
            const float inv = rsqrtf(var + 1e-5f);
            const float sc = foldS[e * K + c], bi = foldB[e * K + c];
            afv[c] = inv * sc;
            bfv[c] = bi - mean * inv * sc;
        }
    }

    int mbase, nbase;
    if constexpr (MT == 64) { mbase = (wv & 1) * 32; nbase = (wv >> 1) * 32; }
    else if constexpr (MT == 32) { mbase = (wv & 1) * 16; nbase = (wv >> 1) * 32; }
    else { mbase = 0; nbase = wv * 16; }

    f32x4 acc[IM][IN];
    #pragma unroll
    for (int im = 0; im < IM; im++)
        #pragma unroll
        for (int in = 0; in < IN; in++)
            #pragma unroll
            for (int r = 0; r < 4; r++) acc[im][in][r] = 0.f;

    const unsigned short* ib = inp + (size_t)(BIN ? b : bs) * K * N;
    const unsigned short* wbH = whi + ((size_t)e * mfull + moff) * K;

    for (int k0 = 0; k0 < KITERS * 32; k0 += 32) {
        __syncthreads();
        for (int i = tid; i < MT * 32; i += 256) {
            const int m = i >> 5, kk = i & 31;
            const bool ok = (k0 + kk < K);
            wtile[m * 40 + kk] = ok ? wbH[(size_t)(m0 + m) * K + k0 + kk]
                                    : (unsigned short)0;
        }
        {
            const int kp = tid >> 4, nq = tid & 15;
            const int k = k0 + kp * 2;
            const int n = n0 + nq * 4;
            unsigned short u0[4] = {0, 0, 0, 0}, u1[4] = {0, 0, 0, 0};
            const bool nv = (n < N);
            if (nv && k < K) {
                const ushort4 t = *(const ushort4*)(ib + (size_t)k * N + n);
                u0[0] = t.x; u0[1] = t.y; u0[2] = t.z; u0[3] = t.w;
            }
            if (nv && k + 1 < K) {
                const ushort4 t = *(const ushort4*)(ib + (size_t)(k + 1) * N + n);
                u1[0] = t.x; u1[1] = t.y; u1[2] = t.z; u1[3] = t.w;
            }
            #pragma unroll
            for (int t = 0; t < 4; t++) {
                float f0, f1;
                if constexpr (FOLD) {
                    f0 = (nv && k < K) ? silu_f(afv[k] * bf2f(u0[t]) + bfv[k]) : 0.f;
                    f1 = (nv && k + 1 < K) ? silu_f(afv[k + 1] * bf2f(u1[t]) + bfv[k + 1]) : 0.f;
                } else {
                    f0 = bf2f(u0[t]); f1 = bf2f(u1[t]);
                }
                intile[kp * 65 + nq * 4 + t] =
                    (unsigned int)f2bf(f0) | ((unsigned int)f2bf(f1) << 16);
            }
        }
        __syncthreads();

        short8v afr[IM];
        #pragma unroll
        for (int im = 0; im < IM; im++) {
            const int m = mbase + im * 16 + l15;
            afr[im] = *(const short8v*)&wtile[m * 40 + quad * 8];
        }
        #pragma unroll
        for (int in = 0; in < IN; in++) {
            union { unsigned int u[4]; short8v s; } bu;
            const int col = nbase + in * 16 + l15;
            #pragma unroll
            for (int i = 0; i < 4; i++) bu.u[i] = intile[(quad * 4 + i) * 65 + col];
            #pragma unroll
            for (int im = 0; im < IM; im++)
                acc[im][in] = __builtin_amdgcn_mfma_f32_16x16x32_bf16(
                    afr[im], bu.s, acc[im][in], 0, 0, 0);
        }
    }

    unsigned short* ob = outp + (size_t)bs * M * N;
    #pragma unroll
    for (int im = 0; im < IM; im++) {
        #pragma unroll
        for (int in = 0; in < IN; in++) {
            const int n = n0 + nbase + in * 16 + l15;
            float s1 = 0.f, s2 = 0.f;
            #pragma unroll
            for (int r = 0; r < 4; r++) {
                const float a = acc[im][in][r];
                s1 += a; s2 += a * a;
            }
            if (n < N) {
                #pragma unroll
                for (int r = 0; r < 4; r++) {
                    const int m = m0 + mbase + im * 16 + quad * 4 + r;
                    ob[(size_t)m * N + n] = f2bf(acc[im][in][r]);
                }
            }
            #pragma unroll
            for (int off = 8; off > 0; off >>= 1) {
                s1 += __shfl_down(s1, off, 16);
                s2 += __shfl_down(s2, off, 16);
            }
            if (l15 == 0) {
                const int gl = (mbase + im * 16) / 4 + quad;
                atomicAdd(&sred[gl * 2 + 0], s1);
                atomicAdd(&sred[gl * 2 + 1], s2);
            }
        }
    }
    __syncthreads();
    for (int i = tid; i < MT / 4; i += 256) {
        float* sp = stats + (((size_t)bs * (mfull / 4) + moff / 4 + mc * (MT / 4) + i)
                             * NCHK + nc) * 2;
        sp[0] = sred[i * 2]; sp[1] = sred[i * 2 + 1];
    }
}

// ============ dw kernel (3x3 stride 1; stages 2,4,5) =======================
template <int CLOC, int CFULL, int H, int W, int NCH, int TPBk, int NCHK1>
__global__ __launch_bounds__(TPBk) void dw_k(
    const unsigned short* __restrict__ raw1, const float* __restrict__ stats1,
    const float* __restrict__ g1s, const float* __restrict__ g1b,
    const float* __restrict__ w2, const int* __restrict__ gidx,
    unsigned short* __restrict__ act2raw, float* __restrict__ stats2, int coff) {
    constexpr int HW = H * W, HP = H + 2, WPL = W + 3;
    constexpr int NPV = HW / 4, NG = NCH / 4, NW = TPBk / 64;
    constexpr int Qc = HW / 4, QT = NCH * Qc, QI = (QT + TPBk - 1) / TPBk;
    constexpr int G1 = CFULL / 4;
    const int gch = blockIdx.x, b = blockIdx.y, slot = blockIdx.z;
    const int bs = b * 2 + slot;
    const int tid = threadIdx.x;
    const int e = rfl(gidx[b * 2 + slot]);
    const int cb0 = gch * NCH;
    const int cg0 = coff + cb0;

    __shared__ float buf1[NCH * HP * WPL];
    __shared__ float w2s[NCH * 9];
    __shared__ float afl[NCH], bfl[NCH];
    __shared__ float red[2 * NG * NW];

    for (int i = tid; i < NCH * HP * WPL; i += TPBk) buf1[i] = 0.f;
    if (tid < NCH * 9) w2s[tid] = w2[((size_t)e * CFULL + cg0) * 9 + tid];
    if (tid < NCH) {
        const int g = (cg0 + tid) >> 2;
        float s1 = 0.f, s2 = 0.f;
        for (int i = 0; i < NCHK1; i++) {
            s1 += stats1[(((size_t)bs * G1 + g) * NCHK1 + i) * 2 + 0];
            s2 += stats1[(((size_t)bs * G1 + g) * NCHK1 + i) * 2 + 1];
        }
        const float mean = s1 / (4.f * HW);
        const float var = s2 / (4.f * HW) - mean * mean;
        const float inv = rsqrtf(var + 1e-5f);
        const float sc = g1s[e * CFULL + cg0 + tid], bi = g1b[e * CFULL + cg0 + tid];
        afl[tid] = inv * sc; bfl[tid] = bi - mean * inv * sc;
    }
    __syncthreads();

    const unsigned short* rb = raw1 + (size_t)bs * CLOC * HW + (size_t)cb0 * HW;
    for (int i = tid; i < NCH * NPV; i += TPBk) {
        const int c = i / NPV, pv = i - c * NPV;
        const int p4 = pv * 4, ph = p4 / W, pwb = p4 - ph * W;
        const ushort4 u = *(const ushort4*)(rb + (size_t)c * HW + p4);
        const float a = afl[c], bb = bfl[c];
        float* bp = &buf1[(c * HP + ph + 1) * WPL + pwb + 1];
        bp[0] = silu_f(a * bf2f(u.x) + bb);
        bp[1] = silu_f(a * bf2f(u.y) + bb);
        bp[2] = silu_f(a * bf2f(u.z) + bb);
        bp[3] = silu_f(a * bf2f(u.w) + bb);
    }
    __syncthreads();

    float st2[2 * NG];
    #pragma unroll
    for (int i = 0; i < 2 * NG; i++) st2[i] = 0.f;
    unsigned short* ao = act2raw + (size_t)bs * CFULL * HW + (size_t)cg0 * HW;
    #pragma unroll
    for (int qi = 0; qi < QI; qi++) {
        const int q = tid + qi * TPBk;
        if (QI * TPBk == QT || q < QT) {
            const int c = q / Qc, qq = q - c * Qc;
            const int oh = qq % H, owb = (qq / H) * 4;
            float o[4] = {0.f, 0.f, 0.f, 0.f};
            #pragma unroll
            for (int kh = 0; kh < 3; kh++) {
                const int base = (c * HP + oh + kh) * WPL + owb;
                float r[6];
                #pragma unroll
                for (int i = 0; i < 6; i++) r[i] = buf1[base + i];
                const float wa = w2s[c * 9 + kh * 3 + 0];
                const float wb = w2s[c * 9 + kh * 3 + 1];
                const float wcc = w2s[c * 9 + kh * 3 + 2];
                #pragma unroll
                for (int t = 0; t < 4; t++)
                    o[t] += wa * r[t] + wb * r[t + 1] + wcc * r[t + 2];
            }
            ushort4 ov = {f2bf(o[0]), f2bf(o[1]), f2bf(o[2]), f2bf(o[3])};
            *(ushort4*)(ao + c * HW + oh * W + owb) = ov;
            #pragma unroll
            for (int t = 0; t < 4; t++) {
                if constexpr (NG == 1) { st2[0] += o[t]; st2[1] += o[t] * o[t]; }
                else {
                    const bool gs = (c >= 4);
                    float a0 = gs ? 0.f : o[t], a1 = gs ? o[t] : 0.f;
                    st2[0] += a0; st2[1] += a0 * a0;
                    st2[2] += a1; st2[3] += a1 * a1;
                }
            }
        }
    }
    bredN<2 * NG, NW>(st2, red);
    if (tid == 0) {
        #pragma unroll
        for (int g = 0; g < NG; g++) {
            stats2[((size_t)bs * G1 + cg0 / 4 + g) * 2 + 0] = st2[g * 2];
            stats2[((size_t)bs * G1 + cg0 / 4 + g) * 2 + 1] = st2[g * 2 + 1];
        }
    }
}

// ================= Stage 1: band pipeline ==================================
__global__ __launch_bounds__(256) void s1_stats(
    const float* __restrict__ xin, const float* __restrict__ w1,
    const int* __restrict__ gidx, float* __restrict__ stats1) {
    const int g = blockIdx.x, b = blockIdx.y, slot = blockIdx.z;
    const int tid = threadIdx.x;
    const int e = rfl(gidx[b * 2 + slot]);
    __shared__ float red[8];
    const float* xb = xin + (size_t)b * 3 * 6400;
    const float* w1e = w1 + ((size_t)e * 32 + g * 4) * 3;
    float wr[4][3];
    #pragma unroll
    for (int c = 0; c < 4; c++)
        #pragma unroll
        for (int k = 0; k < 3; k++) wr[c][k] = rflf(w1e[c * 3 + k]);
    float s[2] = {0.f, 0.f};
    #pragma unroll
    for (int j = 0; j < 7; j++) {
        const int i = j * 256 + tid;
        if (i < 1600) {
            const int p4 = i * 4;
            const float4 v0 = *(const float4*)(xb + p4);
            const float4 v1 = *(const float4*)(xb + 6400 + p4);
            const float4 v2 = *(const float4*)(xb + 12800 + p4);
            const float a0[4] = {v0.x, v0.y, v0.z, v0.w};
            const float a1[4] = {v1.x, v1.y, v1.z, v1.w};
            const float a2[4] = {v2.x, v2.y, v2.z, v2.w};
            #pragma unroll
            for (int t = 0; t < 4; t++)
                #pragma unroll
                for (int c = 0; c < 4; c++) {
                    float a = fmaf(wr[c][0], a0[t], fmaf(wr[c][1], a1[t], wr[c][2] * a2[t]));
                    s[0] += a; s[1] += a * a;
                }
        }
    }
    bredN<2, 4>(s, red);
    if (tid == 0) {
        float* sp = stats1 + ((size_t)(b * 2 + slot) * 8 + g) * 2;
        sp[0] = s[0]; sp[1] = s[1];
    }
}

// Row-interleaved even/odd band kernel; rawdw bf16 out (GN2 folds into GEMM).
__global__ __launch_bounds__(256) void s1_band(
    const float* __restrict__ xin, const float* __restrict__ w1,
    const float* __restrict__ g1s, const float* __restrict__ g1b,
    const float* __restrict__ w2, const int* __restrict__ gidx,
    const float* __restrict__ stats1,
    unsigned short* __restrict__ rawdw, float* __restrict__ stats2) {
    constexpr int NR = 25, RW = 91, EVO = 44;
    const int gb = blockIdx.x;
    const int g = gb >> 2, band = gb & 3;
    const int b = blockIdx.y, slot = blockIdx.z;
    const int tid = threadIdx.x;
    const int e = rfl(gidx[b * 2 + slot]);

    __shared__ float sbuf[4 * NR * RW];
    __shared__ float w2s[196];
    __shared__ float red[8];

    for (int i = tid; i < 4 * NR * RW; i += 256) sbuf[i] = 0.f;
    if (tid < 196) w2s[tid] = w2[((size_t)e * 32 + g * 4) * 49 + tid];

    const float* sp = stats1 + ((size_t)(b * 2 + slot) * 8 + g) * 2;
    const float s1v = rflf(sp[0]), s2v = rflf(sp[1]);
    const float mean = s1v / 25600.f;
    const float var = s2v / 25600.f - mean * mean;
    const float inv = rsqrtf(var + 1e-5f);

    const float* xb = xin + (size_t)b * 3 * 6400;
    const float* w1e = w1 + ((size_t)e * 32 + g * 4) * 3;
    float wr[4][3], sc1r[4], bi1r[4];
    #pragma unroll
    for (int c = 0; c < 4; c++) {
        #pragma unroll
        for (int k = 0; k < 3; k++) wr[c][k] = rflf(w1e[c * 3 + k]);
        sc1r[c] = rflf(g1s[e * 32 + g * 4 + c]);
        bi1r[c] = rflf(g1b[e * 32 + g * 4 + c]);
    }
    const int oh0 = band * 10;
    const int rlo = 2 * oh0 - 3;
    __syncthreads();

    for (int ii = tid; ii < 500; ii += 256) {
        const int p4 = ii * 4;
        const int l = p4 / 80, pw = p4 - l * 80;
        const int r = rlo + l;
        if (r >= 0 && r < 80) {
            const int lrow = (l >> 1) + (l & 1) * 13;
            const float4 v0 = *(const float4*)(xb + r * 80 + pw);
            const float4 v1 = *(const float4*)(xb + 6400 + r * 80 + pw);
            const float4 v2 = *(const float4*)(xb + 12800 + r * 80 + pw);
            const float a0[4] = {v0.x, v0.y, v0.z, v0.w};
            const float a1[4] = {v1.x, v1.y, v1.z, v1.w};
            const float a2[4] = {v2.x, v2.y, v2.z, v2.w};
            #pragma unroll
            for (int c = 0; c < 4; c++) {
                #pragma unroll
                for (int t = 0; t < 4; t++) {
                    float a = fmaf(wr[c][0], a0[t], fmaf(wr[c][1], a1[t], wr[c][2] * a2[t]));
                    float v = silu_f((a - mean) * inv * sc1r[c] + bi1r[c]);
                    const int cc = pw + t + 3;
                    const int sl = (cc & 1) ? EVO + (cc >> 1) : (cc >> 1);
                    sbuf[(c * NR + lrow) * RW + sl] = v;
                }
            }
        }
    }
    __syncthreads();

    float st2[2] = {0.f, 0.f};
    unsigned short* rw = rawdw + (size_t)(b * 2 + slot) * 32 * 1600
                         + (size_t)g * 4 * 1600;
    #pragma unroll
    for (int qi = 0; qi < 2; qi++) {
        const int q = tid + qi * 256;
        if (q < 400) {
            const int c = q / 100;
            const int rem = q - c * 100;
            const int ohl = rem % 10, owb = (rem / 10) * 4;
            float o[4] = {0.f, 0.f, 0.f, 0.f};
            #pragma unroll
            for (int kh = 0; kh < 7; kh++) {
                const int lrow = ohl + (kh >> 1) + (kh & 1) * 13;
                const int base = (c * NR + lrow) * RW;
                const float2 e01 = *(const float2*)&sbuf[base + owb];
                const float2 e23 = *(const float2*)&sbuf[base + owb + 2];
                const float2 e45 = *(const float2*)&sbuf[base + owb + 4];
                const float e6 = sbuf[base + owb + 6];
                const float2 q01 = *(const float2*)&sbuf[base + EVO + owb];
                const float2 q23 = *(const float2*)&sbuf[base + EVO + owb + 2];
                const float2 q45 = *(const float2*)&sbuf[base + EVO + owb + 4];
                const float evr[7] = {e01.x, e01.y, e23.x, e23.y, e45.x, e45.y, e6};
                const float odr[6] = {q01.x, q01.y, q23.x, q23.y, q45.x, q45.y};
                const float w0 = w2s[c * 49 + kh * 7 + 0];
                const float w1v = w2s[c * 49 + kh * 7 + 1];
                const float w2v = w2s[c * 49 + kh * 7 + 2];
                const float w3 = w2s[c * 49 + kh * 7 + 3];
                const float w4 = w2s[c * 49 + kh * 7 + 4];
                const float w5 = w2s[c * 49 + kh * 7 + 5];
                const float w6 = w2s[c * 49 + kh * 7 + 6];
                #pragma unroll
                for (int t = 0; t < 4; t++)
                    o[t] += w0 * evr[t] + w1v * odr[t] + w2v * evr[t + 1]
                          + w3 * odr[t + 1] + w4 * evr[t + 2] + w5 * odr[t + 2]
                          + w6 * evr[t + 3];
            }
            const int oh = oh0 + ohl;
            ushort4 ov = {f2bf(o[0]), f2bf(o[1]), f2bf(o[2]), f2bf(o[3])};
            *(ushort4*)(rw + c * 1600 + oh * 40 + owb) = ov;
            #pragma unroll
            for (int t = 0; t < 4; t++) { st2[0] += o[t]; st2[1] += o[t] * o[t]; }
        }
    }
    bredN<2, 4>(st2, red);
    if (tid == 0) {
        float* s2p = stats2 + (((size_t)(b * 2 + slot) * 8 + g) * 4 + band) * 2;
        s2p[0] = st2[0]; s2p[1] = st2[1];
    }
}

// ======== Stage-3 SLOT-MERGED fused ab (CIN=32, CEXP=128, stride-2 3x3) ====
// One block computes both slots' 4-ch group: x tile loaded ONCE. Grid (gch, b)
// — R15 dispatch order preserved.
__global__ __launch_bounds__(256) void dsc_ab_s3(
    const unsigned short* __restrict__ xin, const float* __restrict__ w1,
    const float* __restrict__ g1s, const float* __restrict__ g1b,
    const float* __restrict__ w2,
    const float* __restrict__ g2s, const float* __restrict__ g2b,
    const int* __restrict__ gidx, unsigned short* __restrict__ act2) {
    constexpr int CIN = 32, CEXP = 128, H = 40, W = 40, HW = 1600;
    constexpr int HO = 20, WO = 20, HWO = 400;
    constexpr int HP = H + 2, WPL = W + 3, EVW = (W + 2) / 2;
    const int gch = blockIdx.x, b = blockIdx.y;
    const int cb0 = gch * 4;
    const int tid = threadIdx.x;
    int ee[2];
    ee[0] = rfl(gidx[b * 2 + 0]);
    ee[1] = rfl(gidx[b * 2 + 1]);

    __shared__ float buf1[4 * HP * WPL];   // 28.9 KB
    __shared__ float w2s[2][36];
    __shared__ float sc2s[2][4], bi2s[2][4];
    __shared__ float red[16];

    for (int i = tid; i < 4 * HP * WPL; i += 256) buf1[i] = 0.f;
    if (tid < 72) {
        const int s = tid / 36, i = tid - s * 36;
        w2s[s][i] = w2[((size_t)ee[s] * CEXP + cb0) * 9 + i];
    }
    if (tid < 8) {
        const int s = tid >> 2, c = tid & 3;
        sc2s[s][c] = g2s[ee[s] * CEXP + cb0 + c];
        bi2s[s][c] = g2b[ee[s] * CEXP + cb0 + c];
    }

    const unsigned short* xb = xin + (size_t)b * CIN * HW;

    float acc[2][4][2][4];
    #pragma unroll
    for (int s = 0; s < 2; s++)
        #pragma unroll
        for (int c = 0; c < 4; c++)
            #pragma unroll
            for (int j = 0; j < 2; j++)
                #pragma unroll
                for (int t = 0; t < 4; t++) acc[s][c][j][t] = 0.f;

    for (int cb = 0; cb < CIN; cb += 4) {
        float wr[2][4][4];
        #pragma unroll
        for (int s = 0; s < 2; s++) {
            const float* w1e = w1 + ((size_t)ee[s] * CEXP + cb0) * CIN;
            #pragma unroll
            for (int c = 0; c < 4; c++)
                #pragma unroll
                for (int k = 0; k < 4; k++)
                    wr[s][c][k] = rflf(w1e[c * CIN + cb + k]);
        }
        #pragma unroll
        for (int j = 0; j < 2; j++) {
            const int pv = tid + j * 256;
            if (pv < 400) {
                #pragma unroll
                for (int k = 0; k < 4; k++) {
                    const ushort4 v4 = *(const ushort4*)(xb + (cb + k) * HW + pv * 4);
                    const float va[4] = {bf2f(v4.x), bf2f(v4.y), bf2f(v4.z), bf2f(v4.w)};
                    #pragma unroll
                    for (int s = 0; s < 2; s++)
                        #pragma unroll
                        for (int c = 0; c < 4; c++)
                            #pragma unroll
                            for (int t = 0; t < 4; t++)
                                acc[s][c][j][t] = fmaf(wr[s][c][k], va[t], acc[s][c][j][t]);
                }
            }
        }
    }
    float st[4] = {0.f, 0.f, 0.f, 0.f};
    #pragma unroll
    for (int s = 0; s < 2; s++)
        #pragma unroll
        for (int c = 0; c < 4; c++)
            #pragma unroll
            for (int j = 0; j < 2; j++)
                #pragma unroll
                for (int t = 0; t < 4; t++) {
                    const float a = acc[s][c][j][t];
                    st[s * 2] += a; st[s * 2 + 1] += a * a;
                }
    bredN<4, 4>(st, red);
    float mg[2], ig[2], sc1r[2][4], bi1r[2][4];
    #pragma unroll
    for (int s = 0; s < 2; s++) {
        mg[s] = st[s * 2] / 6400.f;
        const float var = st[s * 2 + 1] / 6400.f - mg[s] * mg[s];
        ig[s] = rsqrtf(var + 1e-5f);
        #pragma unroll
        for (int c = 0; c < 4; c++) {
            sc1r[s][c] = rflf(g1s[ee[s] * CEXP + cb0 + c]);
            bi1r[s][c] = rflf(g1b[ee[s] * CEXP + cb0 + c]);
        }
    }

    float dacc[2][2][4];
    float st2[4] = {0.f, 0.f, 0.f, 0.f};
    #pragma unroll
    for (int s = 0; s < 2; s++) {
        if (s) __syncthreads();
        #pragma unroll
        for (int j = 0; j < 2; j++) {
            const int pv = tid + j * 256;
            if (pv < 400) {
                const int p4 = pv * 4;
                const int ph = p4 / W, pwb = p4 - ph * W;
                #pragma unroll
                for (int c = 0; c < 4; c++) {
                    #pragma unroll
                    for (int t = 0; t < 4; t++) {
                        const float v = silu_f((acc[s][c][j][t] - mg[s]) * ig[s]
                                               * sc1r[s][c] + bi1r[s][c]);
                        const int j2 = pwb + t + 1;
                        const int col = (j2 & 1) ? EVW + (j2 >> 1) : (j2 >> 1);
                        buf1[(c * HP + ph + 1) * WPL + col] = v;
                    }
                }
            }
        }
        __syncthreads();
        #pragma unroll
        for (int qi = 0; qi < 2; qi++) {
            #pragma unroll
            for (int t = 0; t < 4; t++) dacc[s][qi][t] = 0.f;
            const int q = tid + qi * 256;
            if (q < 400) {
                const int c = q / 100, qq = q - c * 100;
                const int oh = qq % HO, owb = (qq / HO) * 4;
                float o[4] = {0.f, 0.f, 0.f, 0.f};
                #pragma unroll
                for (int kh = 0; kh < 3; kh++) {
                    const int base = (c * HP + 2 * oh + kh) * WPL;
                    float ev[5], od[4];
                    #pragma unroll
                    for (int i = 0; i < 5; i++) ev[i] = buf1[base + owb + i];
                    #pragma unroll
                    for (int i = 0; i < 4; i++) od[i] = buf1[base + EVW + owb + i];
                    const float wa = w2s[s][c * 9 + kh * 3 + 0];
                    const float wb = w2s[s][c * 9 + kh * 3 + 1];
                    const float wcc = w2s[s][c * 9 + kh * 3 + 2];
                    #pragma unroll
                    for (int t = 0; t < 4; t++)
                        o[t] += wa * ev[t] + wb * od[t] + wcc * ev[t + 1];
                }
                #pragma unroll
                for (int t = 0; t < 4; t++) {
                    dacc[s][qi][t] = o[t];
                    st2[s * 2] += o[t]; st2[s * 2 + 1] += o[t] * o[t];
                }
            }
        }
    }
    bredN<4, 4>(st2, red);
    #pragma unroll
    for (int s = 0; s < 2; s++) {
        const float m2 = st2[s * 2] / 1600.f;
        const float var2 = st2[s * 2 + 1] / 1600.f - m2 * m2;
        const float i2 = rsqrtf(var2 + 1e-5f);
        unsigned short* ao = act2 + ((size_t)(b * 2 + s) * CEXP + cb0) * HWO;
        #pragma unroll
        for (int qi = 0; qi < 2; qi++) {
            const int q = tid + qi * 256;
            if (q < 400) {
                const int c = q / 100, qq = q - c * 100;
                const int oh = qq % HO, owb = (qq / HO) * 4;
                const float sc = sc2s[s][c], bi = bi2s[s][c];
                ushort4 ov;
                ov.x = f2bf(silu_f((dacc[s][qi][0] - m2) * i2 * sc + bi));
                ov.y = f2bf(silu_f((dacc[s][qi][1] - m2) * i2 * sc + bi));
                ov.z = f2bf(silu_f((dacc[s][qi][2] - m2) * i2 * sc + bi));
                ov.w = f2bf(silu_f((dacc[s][qi][3] - m2) * i2 * sc + bi));
                *(ushort4*)(ao + c * HWO + oh * WO + owb) = ov;
            }
        }
    }
}

// k3m: fold GN3 stat partials -> (A,B) per channel, combine slots. raw3 bf16.
template <int COUT, int HWO, int PXC, bool PATCH>
__global__ __launch_bounds__(256) void pw3_k3m(
    const unsigned short* __restrict__ raw3, const float* __restrict__ statsw,
    const float* __restrict__ g3s, const float* __restrict__ g3b,
    const int* __restrict__ gidx, const float* __restrict__ gw,
    const float* __restrict__ ppe, float* __restrict__ outf,
    unsigned short* __restrict__ outb) {
    constexpr int G = COUT / 4;
    constexpr int Q = HWO / 4;
    const int gg = blockIdx.x, b = blockIdx.y;
    const int tid = threadIdx.x;

    float A[2][4], Bv[2][4];
    #pragma unroll
    for (int slot = 0; slot < 2; slot++) {
        const int e = rfl(gidx[b * 2 + slot]);
        const float wgt = rflf(gw[b * 2 + slot]);
        const float* sp = statsw + ((size_t)(b * 2 + slot) * G + gg) * PXC * 2;
        float s1 = 0.f, s2 = 0.f;
        for (int i = 0; i < PXC; i++) { s1 += rflf(sp[i * 2]); s2 += rflf(sp[i * 2 + 1]); }
        const float mean = s1 / (4.f * HWO);
        const float var = s2 / (4.f * HWO) - mean * mean;
        const float inv = rsqrtf(var + 1e-5f);
        #pragma unroll
        for (int i = 0; i < 4; i++) {
            const int c = gg * 4 + i;
            const float sc = rflf(g3s[e * COUT + c]);
            const float bi = rflf(g3b[e * COUT + c]);
            A[slot][i] = wgt * inv * sc;
            Bv[slot][i] = wgt * (bi - mean * inv * sc);
        }
    }

    #pragma unroll
    for (int i = 0; i < 4; i++) {
        const int c = gg * 4 + i;
        const unsigned short* r0 = raw3 + ((size_t)(b * 2 + 0) * COUT + c) * HWO;
        const unsigned short* r1 = raw3 + ((size_t)(b * 2 + 1) * COUT + c) * HWO;
        for (int q = tid; q < Q; q += 256) {
            const int p4 = q * 4;
            const ushort4 u0 = *(const ushort4*)(r0 + p4);
            const ushort4 u1 = *(const ushort4*)(r1 + p4);
            const float v0[4] = {bf2f(u0.x), bf2f(u0.y), bf2f(u0.z), bf2f(u0.w)};
            const float v1[4] = {bf2f(u1.x), bf2f(u1.y), bf2f(u1.z), bf2f(u1.w)};
            float o[4];
            #pragma unroll
            for (int t = 0; t < 4; t++)
                o[t] = fmaf(A[0][i], v0[t], Bv[0][i]) + fmaf(A[1][i], v1[t], Bv[1][i]);
            if constexpr (!PATCH) {
                ushort4 ov = {f2bf(o[0]), f2bf(o[1]), f2bf(o[2]), f2bf(o[3])};
                *(ushort4*)(outb + ((size_t)b * COUT + c) * HWO + p4) = ov;
            } else {
                const int ph = p4 / 20, pw0 = p4 - ph * 20;
                const int p = (ph >> 2) * 5 + (pw0 >> 2);
                const int dbase = ((ph & 3) * 4) * 32 + c;
                float* op = outf + ((size_t)b * 25 + p) * 512;
                const float* pp = ppe + p * 512;
                #pragma unroll
                for (int jj = 0; jj < 4; jj++)
                    op[dbase + jj * 32] = o[jj] + pp[dbase + jj * 32];
            }
        }
    }
    if (PATCH && gg == 0 && b == 0 && tid == 0) outf[64 * 25 * 512] = 0.f;
}

extern "C" void kernel_launch(void* const* d_in, const int* in_sizes, int n_in,
                              void* d_out, int out_size, void* d_ws, size_t ws_size,
                              hipStream_t stream) {
    const float* gate_input = (const float*)d_in[0];
    const float* expert_input = (const float*)d_in[1];
    const float* ppe = (const float*)d_in[2];
    const int* taskp = (const int*)d_in[53];
    auto in = [&](int s, int k) { return (const float*)d_in[3 + s * 10 + k]; };
    // k: 0 wg, 1 w1, 2 g1s, 3 g1b, 4 w2, 5 g2s, 6 g2b, 7 w3, 8 g3s, 9 g3b

    char* ws = (char*)d_ws;
    int* gidx = (int*)ws;
    float* gw = (float*)(ws + 4096);
    size_t off = 8192;
    unsigned short* x0 = (unsigned short*)(ws + off); off += (size_t)8 << 20;
    unsigned short* x1 = (unsigned short*)(ws + off); off += (size_t)8 << 20;
    unsigned short* act2 = (unsigned short*)(ws + off); off += (size_t)27 << 20;
    char* bufA = ws + off; off += (size_t)27 << 20;   // raw1 / raw3 / s1 rawdw
    float* stats1 = (float*)(ws + off); off += (size_t)2 << 20;
    float* stats2 = (float*)(ws + off); off += 262144;
    float* stats3 = (float*)(ws + off); off += (size_t)1 << 20;
    float* st1a = (float*)(ws + off); off += 65536;
    float* st1b = (float*)(ws + off); off += 65536;
    unsigned short* whi = (unsigned short*)(ws + off); off += 487424 * 2;
    float* outp = (float*)d_out;
    unsigned short* bufA16 = (unsigned short*)bufA;

    WSrcs wsrc;
    wsrc.p[0] = in(0, 7); wsrc.p[1] = in(1, 1); wsrc.p[2] = in(1, 7);
    wsrc.p[3] = in(2, 1); wsrc.p[4] = in(2, 7); wsrc.p[5] = in(3, 1);
    wsrc.p[6] = in(3, 7); wsrc.p[7] = in(4, 1); wsrc.p[8] = in(4, 7);

    GatePtrs gp;
    for (int s = 0; s < 5; s++) gp.wg[s] = in(s, 0);
    gate_kernel<<<5, 64, 0, stream>>>(gate_input, gp, taskp, gidx, gw);
    wprep<<<(487424 + 255) / 256, 256, 0, stream>>>(wsrc, whi);

    // ---- Stage 1: stats -> band(rawdw bf16) -> GEMM(fold GN2) -> k3m ----
    s1_stats<<<dim3(8, 64, 2), 256, 0, stream>>>(expert_input, in(0, 1),
                                                 gidx + 0 * 128, st1a);
    s1_band<<<dim3(32, 64, 2), 256, 0, stream>>>(
        expert_input, in(0, 1), in(0, 2), in(0, 3), in(0, 4),
        gidx + 0 * 128, st1a, bufA16, st1b);
    gemm_bf16<16, 32, 1600, 16, 25, true, false><<<dim3(25, 64, 2), 256, 0, stream>>>(
        bufA16, whi + 0, gidx + 0 * 128, st1b, in(0, 5), in(0, 6),
        act2, stats3, 16, 0, 4);
    pw3_k3m<16, 1600, 25, false><<<dim3(4, 64), 256, 0, stream>>>(
        act2, stats3, in(0, 8), in(0, 9), gidx + 0 * 128,
        gw + 0 * 128, ppe, nullptr, x0);

    // ---- Stage 2 ----
    gemm_bf16<64, 16, 1600, 64, 25, false, true><<<dim3(25, 64, 2), 256, 0, stream>>>(
        x0, whi + 4096, gidx + 1 * 128, nullptr, nullptr, nullptr,
        bufA16, stats1, 64, 0, 1);
    dw_k<64, 64, 40, 40, 4, 256, 25><<<dim3(16, 64, 2), 256, 0, stream>>>(
        bufA16, stats1, in(1, 2), in(1, 3), in(1, 4),
        gidx + 1 * 128, act2, stats2, 0);
    gemm_bf16<32, 64, 1600, 32, 25, true, false><<<dim3(25, 64, 2), 256, 0, stream>>>(
        act2, whi + 12288, gidx + 1 * 128, stats2, in(1, 5), in(1, 6),
        bufA16, stats3, 32, 0, 1);
    pw3_k3m<32, 1600, 25, false><<<dim3(8, 64), 256, 0, stream>>>(
        bufA16, stats3, in(1, 8), in(1, 9), gidx + 1 * 128,
        gw + 1 * 128, ppe, nullptr, x1);

    // ---- Stage 3: slot-merged fused ab + MFMA pw3 (R15 grid order) ----
    dsc_ab_s3<<<dim3(32, 64), 256, 0, stream>>>(
        x1, in(2, 1), in(2, 2), in(2, 3), in(2, 4), in(2, 5), in(2, 6),
        gidx + 2 * 128, act2);
    gemm_bf16<64, 128, 400, 64, 7, false, false><<<dim3(7, 64, 2), 256, 0, stream>>>(
        act2, whi + 61440, gidx + 2 * 128, nullptr, nullptr, nullptr,
        bufA16, stats3, 64, 0, 1);
    pw3_k3m<64, 400, 7, false><<<dim3(16, 64), 256, 0, stream>>>(
        bufA16, stats3, in(2, 8), in(2, 9), gidx + 2 * 128,
        gw + 2 * 128, ppe, nullptr, x0);

    // ---- Stage 4 ----
    gemm_bf16<256, 64, 400, 64, 7, false, true><<<dim3(28, 64, 2), 256, 0, stream>>>(
        x0, whi + 126976, gidx + 3 * 128, nullptr, nullptr, nullptr,
        bufA16, stats1, 256, 0, 1);
    dw_k<256, 256, 20, 20, 8, 128, 7><<<dim3(32, 64, 2), 128, 0, stream>>>(
        bufA16, stats1, in(3, 2), in(3, 3), in(3, 4),
        gidx + 3 * 128, act2, stats2, 0);
    gemm_bf16<64, 256, 400, 64, 7, true, false><<<dim3(7, 64, 2), 256, 0, stream>>>(
        act2, whi + 258048, gidx + 3 * 128, stats2, in(3, 5), in(3, 6),
        bufA16, stats3, 64, 0, 1);
    pw3_k3m<64, 400, 7, false><<<dim3(16, 64), 256, 0, stream>>>(
        bufA16, stats3, in(3, 8), in(3, 9), gidx + 3 * 128,
        gw + 3 * 128, ppe, nullptr, x1);

    // ---- Stage 5 (+ fused patchify) ----
    gemm_bf16<128, 64, 400, 64, 7, false, true><<<dim3(14, 64, 2), 256, 0, stream>>>(
        x1, whi + 389120, gidx + 4 * 128, nullptr, nullptr, nullptr,
        bufA16, stats1, 128, 0, 1);
    dw_k<128, 128, 20, 20, 8, 128, 7><<<dim3(16, 64, 2), 128, 0, stream>>>(
        bufA16, stats1, in(4, 2), in(4, 3), in(4, 4),
        gidx + 4 * 128, act2, stats2, 0);
    gemm_bf16<32, 128, 400, 32, 7, true, false><<<dim3(7, 64, 2), 256, 0, stream>>>(
        act2, whi + 454656, gidx + 4 * 128, stats2, in(4, 5), in(4, 6),
        bufA16, stats3, 32, 0, 1);
    pw3_k3m<32, 400, 7, true><<<dim3(8, 64), 256, 0, stream>>>(
        bufA16, stats3, in(4, 8), in(4, 9), gidx + 4 * 128,
        gw + 4 * 128, ppe, outp, nullptr);
}